// Round 1
// baseline (155.323 us; speedup 1.0000x reference)
//
#include <hip/hip_runtime.h>

#define WAVES_PER_BLOCK 4
#define BLOCK_SIZE (WAVES_PER_BLOCK * 64)
#define NUM_BLOCKS 2048
#define EMBED 128
#define VOCAB 50257

// One wave per token (grid-strided). Lane l holds emb[t] elements [2l, 2l+1].
// For each Huffman path node: gather fc row (coalesced float2), butterfly
// reduce the dot across 64 lanes, stable BCE, accumulate sum & count.
__global__ __launch_bounds__(BLOCK_SIZE) void hs_main(
    const float* __restrict__ emb,        // [T, 128]
    const int*   __restrict__ target,     // [T]
    const float* __restrict__ fc,         // [V-1, 128]
    const int*   __restrict__ path_idx,   // [V, D]
    const float* __restrict__ path_code,  // [V, D]
    const float* __restrict__ path_mask,  // [V, D]
    int T, int D,
    float* __restrict__ partial_b,        // [gridDim.x]
    float* __restrict__ partial_c)        // [gridDim.x]
{
    __shared__ float sb[WAVES_PER_BLOCK];
    __shared__ float sc[WAVES_PER_BLOCK];

    const int wave = threadIdx.x >> 6;
    const int lane = threadIdx.x & 63;
    const int gw   = blockIdx.x * WAVES_PER_BLOCK + wave;   // global wave id
    const int nw   = gridDim.x * WAVES_PER_BLOCK;           // total waves

    float accb = 0.0f;
    float accc = 0.0f;

    for (int t = gw; t < T; t += nw) {
        const int v = target[t];
        const float2 e = ((const float2*)(emb + (size_t)t * EMBED))[lane];

        const int*   ip = path_idx  + (size_t)v * D;
        const float* cp = path_code + (size_t)v * D;
        const float* mp = path_mask + (size_t)v * D;

        for (int d = 0; d < D; ++d) {
            const float m = mp[d];            // wave-uniform address -> broadcast
            if (m == 0.0f) break;             // mask is prefix-contiguous
            const int   row = ip[d];
            const float c   = cp[d];

            const float2 w = ((const float2*)(fc + (size_t)row * EMBED))[lane];
            float dot = fmaf(e.x, w.x, e.y * w.y);

            // 64-lane butterfly reduce; every lane ends with the full sum
            #pragma unroll
            for (int o = 32; o > 0; o >>= 1)
                dot += __shfl_xor(dot, o);

            // stable BCE-with-logits (same value on all lanes; no divergence)
            const float bce = fmaxf(dot, 0.0f) - dot * c
                            + log1pf(expf(-fabsf(dot)));
            accb += bce;
            accc += 1.0f;
        }
    }

    if (lane == 0) { sb[wave] = accb; sc[wave] = accc; }
    __syncthreads();
    if (threadIdx.x == 0) {
        float b = 0.0f, c = 0.0f;
        #pragma unroll
        for (int i = 0; i < WAVES_PER_BLOCK; ++i) { b += sb[i]; c += sc[i]; }
        partial_b[blockIdx.x] = b;
        partial_c[blockIdx.x] = c;
    }
}

// Deterministic single-block finalize: double-precision sums, then divide.
__global__ __launch_bounds__(256) void hs_finalize(
    const float* __restrict__ pb,
    const float* __restrict__ pc,
    int n, float* __restrict__ out)
{
    __shared__ double rb[256];
    __shared__ double rc[256];

    double sb = 0.0, sc = 0.0;
    for (int i = threadIdx.x; i < n; i += 256) {
        sb += (double)pb[i];
        sc += (double)pc[i];
    }
    rb[threadIdx.x] = sb;
    rc[threadIdx.x] = sc;
    __syncthreads();

    for (int s = 128; s > 0; s >>= 1) {
        if (threadIdx.x < s) {
            rb[threadIdx.x] += rb[threadIdx.x + s];
            rc[threadIdx.x] += rc[threadIdx.x + s];
        }
        __syncthreads();
    }
    if (threadIdx.x == 0) out[0] = (float)(rb[0] / rc[0]);
}

extern "C" void kernel_launch(void* const* d_in, const int* in_sizes, int n_in,
                              void* d_out, int out_size, void* d_ws, size_t ws_size,
                              hipStream_t stream) {
    const float* emb   = (const float*)d_in[0];
    const int*   tgt   = (const int*)  d_in[1];
    const float* fc    = (const float*)d_in[2];
    const int*   pidx  = (const int*)  d_in[3];
    const float* pcode = (const float*)d_in[4];
    const float* pmask = (const float*)d_in[5];

    const int T = in_sizes[1];            // 128*1*256 = 32768 tokens
    const int D = in_sizes[3] / VOCAB;    // padded max path depth

    float* pb = (float*)d_ws;             // [NUM_BLOCKS]
    float* pc = pb + NUM_BLOCKS;          // [NUM_BLOCKS]
    float* out = (float*)d_out;

    hs_main<<<NUM_BLOCKS, BLOCK_SIZE, 0, stream>>>(
        emb, tgt, fc, pidx, pcode, pmask, T, D, pb, pc);
    hs_finalize<<<1, 256, 0, stream>>>(pb, pc, NUM_BLOCKS, out);
}

// Round 2
// 45.221 us; speedup vs baseline: 3.4348x; 3.4348x over previous
//
#include <hip/hip_runtime.h>

#define TILE    32
#define BLOCK   256
#define EMBED   128
#define VOCAB   50257
#define ESTRIDE 132   // 128 + 4 pad floats: keeps 16B alignment, spreads banks

// Each block: stage 32 tokens' embeddings in LDS, then threads each own one
// (token, path-node) item: in-lane 128-length dot (float4), BCE once per node.
__global__ __launch_bounds__(BLOCK) void hs_main(
    const float* __restrict__ emb,        // [T, 128]
    const int*   __restrict__ target,     // [T]
    const float* __restrict__ fc,         // [V-1, 128]
    const int*   __restrict__ path_idx,   // [V, D]
    const float* __restrict__ path_code,  // [V, D]
    const float* __restrict__ path_mask,  // [V, D]
    int T, int D,
    float* __restrict__ partial_b,        // [gridDim.x]
    float* __restrict__ partial_c)        // [gridDim.x]
{
    __shared__ float se[TILE * ESTRIDE];
    __shared__ int   st[TILE];
    __shared__ float sb[BLOCK / 64];
    __shared__ float sc[BLOCK / 64];

    const int tok0 = blockIdx.x * TILE;
    const int ntok = min(TILE, T - tok0);

    // Stage emb tile (tokens are contiguous rows) into padded LDS.
    const float4* g4 = (const float4*)(emb + (size_t)tok0 * EMBED);
    for (int j = threadIdx.x; j < ntok * (EMBED / 4); j += BLOCK) {
        float4 v = g4[j];
        const int f  = j * 4;
        const int tk = f >> 7;      // /128
        const int kk = f & 127;
        *(float4*)&se[tk * ESTRIDE + kk] = v;
    }
    if (threadIdx.x < ntok) st[threadIdx.x] = target[tok0 + threadIdx.x];
    __syncthreads();

    float accb = 0.0f, accc = 0.0f;

    const int items = TILE * D;
    for (int it = threadIdx.x; it < items; it += BLOCK) {
        const int d  = it >> 5;     // item = d*TILE + tk (d-major)
        const int tk = it & (TILE - 1);
        if (tk < ntok) {
            const int v = st[tk];
            const size_t po = (size_t)v * D + d;
            const float m = path_mask[po];
            if (m != 0.0f) {
                const int   row = path_idx[po];
                const float c   = path_code[po];
                const float4* w4 = (const float4*)(fc + (size_t)row * EMBED);
                const float*  e  = &se[tk * ESTRIDE];
                float s0 = 0.f, s1 = 0.f, s2 = 0.f, s3 = 0.f;
                #pragma unroll 8
                for (int k = 0; k < EMBED / 4; ++k) {
                    const float4 w  = w4[k];
                    const float4 ev = *(const float4*)&e[4 * k];
                    s0 = fmaf(ev.x, w.x, s0);
                    s1 = fmaf(ev.y, w.y, s1);
                    s2 = fmaf(ev.z, w.z, s2);
                    s3 = fmaf(ev.w, w.w, s3);
                }
                const float x = (s0 + s1) + (s2 + s3);
                accb += fmaxf(x, 0.0f) - x * c + log1pf(expf(-fabsf(x)));
                accc += 1.0f;
            }
        }
    }

    // One reduction per block (not per node).
    #pragma unroll
    for (int o = 32; o > 0; o >>= 1) {
        accb += __shfl_xor(accb, o);
        accc += __shfl_xor(accc, o);
    }
    const int wave = threadIdx.x >> 6;
    const int lane = threadIdx.x & 63;
    if (lane == 0) { sb[wave] = accb; sc[wave] = accc; }
    __syncthreads();
    if (threadIdx.x == 0) {
        float b = 0.f, c = 0.f;
        #pragma unroll
        for (int i = 0; i < BLOCK / 64; ++i) { b += sb[i]; c += sc[i]; }
        partial_b[blockIdx.x] = b;
        partial_c[blockIdx.x] = c;
    }
}

// Deterministic single-block finalize: double-precision sums, then divide.
__global__ __launch_bounds__(256) void hs_finalize(
    const float* __restrict__ pb,
    const float* __restrict__ pc,
    int n, float* __restrict__ out)
{
    __shared__ double rb[256];
    __shared__ double rc[256];

    double sbv = 0.0, scv = 0.0;
    for (int i = threadIdx.x; i < n; i += 256) {
        sbv += (double)pb[i];
        scv += (double)pc[i];
    }
    rb[threadIdx.x] = sbv;
    rc[threadIdx.x] = scv;
    __syncthreads();

    for (int s = 128; s > 0; s >>= 1) {
        if (threadIdx.x < s) {
            rb[threadIdx.x] += rb[threadIdx.x + s];
            rc[threadIdx.x] += rc[threadIdx.x + s];
        }
        __syncthreads();
    }
    if (threadIdx.x == 0) out[0] = (float)(rb[0] / rc[0]);
}

extern "C" void kernel_launch(void* const* d_in, const int* in_sizes, int n_in,
                              void* d_out, int out_size, void* d_ws, size_t ws_size,
                              hipStream_t stream) {
    const float* emb   = (const float*)d_in[0];
    const int*   tgt   = (const int*)  d_in[1];
    const float* fc    = (const float*)d_in[2];
    const int*   pidx  = (const int*)  d_in[3];
    const float* pcode = (const float*)d_in[4];
    const float* pmask = (const float*)d_in[5];

    const int T = in_sizes[1];            // 32768 tokens
    const int D = in_sizes[3] / VOCAB;    // padded max path depth

    const int nblocks = (T + TILE - 1) / TILE;   // 1024

    float* pb = (float*)d_ws;
    float* pc = pb + nblocks;
    float* out = (float*)d_out;

    hs_main<<<nblocks, BLOCK, 0, stream>>>(
        emb, tgt, fc, pidx, pcode, pmask, T, D, pb, pc);
    hs_finalize<<<1, 256, 0, stream>>>(pb, pc, nblocks, out);
}